// Round 1
// baseline (12181.001 us; speedup 1.0000x reference)
//
#include <hip/hip_runtime.h>
#include <stddef.h>

// CFRMClassifier R5: MFMA batched GRU scan. 16 blocks; block owns 32 h-indices
// (96 gate rows) for ALL 64 batches. Per wave = (batch-tile, i-half): r/z gate
// weight fragments persistent in 128 VGPRs, n-gate frags in 32KB LDS (frag-order,
// conflict-free). h exchanged through LLC as bf16 with relaxed agent atomics;
// per-WAVE flags, no __syncthreads in the t-loop. 4 independent batch rings.

typedef unsigned short u16;
typedef unsigned long long u64t;
typedef short s8v __attribute__((ext_vector_type(8)));
typedef float f4v __attribute__((ext_vector_type(4)));

#define B_ 64
#define T_ 1024
#define H_ 512
#define G_ 1536
#define C_ 32
#define NCLS_ 1000
#define KCLS_ 16448

#define AGENT __HIP_MEMORY_SCOPE_AGENT
#define MFMA16(a, b, c) __builtin_amdgcn_mfma_f32_16x16x32_bf16(a, b, c, 0, 0, 0)

__device__ __forceinline__ u16 f2bf(float f) {
    unsigned u = __float_as_uint(f);
    unsigned r = (u + 0x7fffu + ((u >> 16) & 1u)) >> 16;
    return (u16)r;
}
__device__ __forceinline__ float b2f(u16 x) { return __uint_as_float(((unsigned)x) << 16); }
__device__ __forceinline__ float bflo(unsigned u) { return __uint_as_float(u << 16); }
__device__ __forceinline__ float bfhi(unsigned u) { return __uint_as_float(u & 0xffff0000u); }
__device__ __forceinline__ float sigmoidf_(float x) { return 1.0f / (1.0f + __expf(-x)); }
__device__ __forceinline__ float tanhf_(float x) { return 1.0f - 2.0f / (1.0f + __expf(2.0f * x)); }

__device__ __forceinline__ s8v pull16(const u16* p) {
    union { u64t u[2]; s8v v; } x;
    x.u[0] = __hip_atomic_load((const u64t*)p, __ATOMIC_RELAXED, AGENT);
    x.u[1] = __hip_atomic_load((const u64t*)(p + 4), __ATOMIC_RELAXED, AGENT);
    return x.v;
}

// ---------- prep kernels ----------
__global__ void k_cast_wih(const float* __restrict__ src, u16* __restrict__ dst) {
    int i = blockIdx.x * 256 + threadIdx.x;
    if (i < G_ * H_) dst[i] = f2bf(src[i]);
}

// Apk[blk 16][ihalf 2][gate 3][kstep 16][lane 64] = uint4 of 8 bf16:
// w_hh[row = gate*512 + blk*32 + ihalf*16 + (lane&15)][k = kstep*32 + (lane>>4)*8 + 0..7]
// == the exact per-lane A-fragment for mfma_f32_16x16x32_bf16.
__global__ void k_packA(const float* __restrict__ w_hh, uint4* __restrict__ Apk) {
    int idx = blockIdx.x * 256 + threadIdx.x;  // 16*2*3*16*64 = 98304
    if (idx >= 98304) return;
    int lane = idx & 63;
    int kstep = (idx >> 6) & 15;
    int g10 = idx >> 10;
    int gate = g10 % 3;
    int bi = g10 / 3;
    int ih = bi & 1;
    int blk = bi >> 1;
    int lm = lane & 15, q = lane >> 4;
    int row = gate * 512 + blk * 32 + ih * 16 + lm;
    int k0 = kstep * 32 + q * 8;
    const float* wr = w_hh + (size_t)row * H_ + k0;
    uint4 v;
    v.x = (unsigned)f2bf(wr[0]) | ((unsigned)f2bf(wr[1]) << 16);
    v.y = (unsigned)f2bf(wr[2]) | ((unsigned)f2bf(wr[3]) << 16);
    v.z = (unsigned)f2bf(wr[4]) | ((unsigned)f2bf(wr[5]) << 16);
    v.w = (unsigned)f2bf(wr[6]) | ((unsigned)f2bf(wr[7]) << 16);
    Apk[idx] = v;
}

__global__ void k_decay(float* __restrict__ decay) {
    int t = blockIdx.x * 256 + threadIdx.x;
    if (t < T_) decay[t] = powf(0.85f, (float)(T_ - 1 - t));
}

__global__ void k_zero(float* __restrict__ p, int n) {
    int i = blockIdx.x * 256 + threadIdx.x;
    if (i < n) p[i] = 0.f;
}

// ---------- embedding gather + bf16 cast ----------
__global__ __launch_bounds__(256) void k_embed(const int* __restrict__ tokens,
                                               const float* __restrict__ emb,
                                               u16* __restrict__ X) {
    int g = blockIdx.x * 256 + threadIdx.x;
    int m = g >> 6, c8 = g & 63;
    int tok = tokens[m];
    const float4* src = (const float4*)(emb + (size_t)tok * H_ + c8 * 8);
    float4 f0 = src[0], f1 = src[1];
    uint4 pk;
    pk.x = (unsigned)f2bf(f0.x) | ((unsigned)f2bf(f0.y) << 16);
    pk.y = (unsigned)f2bf(f0.z) | ((unsigned)f2bf(f0.w) << 16);
    pk.z = (unsigned)f2bf(f1.x) | ((unsigned)f2bf(f1.y) << 16);
    pk.w = (unsigned)f2bf(f1.z) | ((unsigned)f2bf(f1.w) << 16);
    *(uint4*)(X + (size_t)m * H_ + c8 * 8) = pk;
}

// ---------- xp GEMM (bf16 MFMA) ----------
__global__ __launch_bounds__(256) void k_xp(const u16* __restrict__ X,
                                            const u16* __restrict__ Wih,
                                            const float* __restrict__ b_ih,
                                            u16* __restrict__ xp) {
    __shared__ u16 Bs[128 * 48];
    int tid = threadIdx.x;
    int bid = blockIdx.x;
    int m0 = (bid / 12) * 64;
    int n0 = (bid % 12) * 128;
    int w = tid >> 6, lane = tid & 63;
    int lm = lane & 15, q = lane >> 4;
    f4v acc[8];
#pragma unroll
    for (int i = 0; i < 8; i++) acc[i] = (f4v){0.f, 0.f, 0.f, 0.f};
    int arow = m0 + w * 16 + lm;
    const u16* Aptr = X + (size_t)arow * H_ + q * 8;
    int srow = tid >> 1, shalf = tid & 1;
    for (int kk = 0; kk < H_; kk += 32) {
        const uint4* src = (const uint4*)(Wih + (size_t)(n0 + srow) * H_ + kk + shalf * 16);
        uint4 v0 = src[0], v1 = src[1];
        uint4* dst = (uint4*)(Bs + srow * 48 + shalf * 16);
        dst[0] = v0; dst[1] = v1;
        __syncthreads();
        s8v a = *(const s8v*)(Aptr + kk);
#pragma unroll
        for (int nt = 0; nt < 8; nt++) {
            s8v bf = *(const s8v*)(Bs + (nt * 16 + lm) * 48 + q * 8);
            acc[nt] = MFMA16(a, bf, acc[nt]);
        }
        __syncthreads();
    }
#pragma unroll
    for (int nt = 0; nt < 8; nt++) {
        int col = n0 + nt * 16 + lm;
        float bias = b_ih[col];
#pragma unroll
        for (int r = 0; r < 4; r++) {
            int row = m0 + w * 16 + q * 4 + r;
            xp[(size_t)row * G_ + col] = f2bf(acc[nt][r] + bias);
        }
    }
}

// ---------- MFMA batched GRU scan ----------
// grid 16, 512 threads (8 waves). Block owns i-range [32*blk, 32*blk+32).
// Wave w: btile = w>>1 (batch rows btile*16..+16), ihalf = w&1 (i sub-range 16).
// Lane (q = l>>4, lm = l&15): D-tile element = (row i-off q*4+j, col batch lm).
// MFMA: D[i-row][batch] += sum_k W[i-row][k] * h[batch][k]:
//   A-frag (W): persistent regs Ar/Az (gate r,z) + LDS AnL (gate n).
//   B-frag (h): pulled from LLC hx[par][b][k] bf16 via relaxed agent atomics.
// Per-wave flags[btile][blk][ihalf]; 4 independent batch rings; no barriers in loop.
__global__ __launch_bounds__(512, 2) void k_scan_mfma(const uint4* __restrict__ Apk,
                                                      const u16* __restrict__ xp,
                                                      const float* __restrict__ b_hh,
                                                      float* __restrict__ hseq,
                                                      u16* __restrict__ hx,
                                                      unsigned* __restrict__ flags) {
    int blk = blockIdx.x;
    int tid = threadIdx.x;
    int w = tid >> 6, lane = tid & 63;
    int btile = w >> 1, ihalf = w & 1;
    int q = lane >> 4, lm = lane & 15;
    int i0 = blk * 32;
    int b = btile * 16 + lm;            // batch column this lane owns (D col; B-frag row)
    int ibase = i0 + ihalf * 16 + q * 4;  // first of 4 consecutive i this lane owns

    // n-gate A-fragments in LDS, already in frag order: [ihalf][kstep][lane] uint4.
    __shared__ uint4 AnL[2 * 16 * 64];
    for (int r = tid; r < 2048; r += 512) {
        int ih = r >> 10, rest = r & 1023;
        AnL[r] = Apk[(size_t)((blk * 2 + ih) * 3 + 2) * 1024 + rest];
    }

    // r/z-gate A-fragments persistent in registers (static indexing only!).
    const uint4* apb = Apk + (size_t)(blk * 2 + ihalf) * 3 * 1024;
    s8v Ar[16], Az[16];
#pragma unroll
    for (int k = 0; k < 16; k++) Ar[k] = *(const s8v*)(apb + k * 64 + lane);
#pragma unroll
    for (int k = 0; k < 16; k++) Az[k] = *(const s8v*)(apb + 1024 + k * 64 + lane);

    float bhr[4], bhz[4], bhn[4];
#pragma unroll
    for (int j = 0; j < 4; j++) {
        bhr[j] = b_hh[ibase + j];
        bhz[j] = b_hh[512 + ibase + j];
        bhn[j] = b_hh[1024 + ibase + j];
    }

    // xp: lane reads 4 consecutive bf16 per gate (uint2), prefetched 1 step ahead.
    const u16* xpb = xp + (size_t)b * T_ * G_ + ibase;
    uint2 xR = *(const uint2*)(xpb);
    uint2 xZ = *(const uint2*)(xpb + 512);
    uint2 xN = *(const uint2*)(xpb + 1024);

    const unsigned* fpoll = flags + btile * 32;             // 32 flags of this ring
    unsigned* fself = flags + btile * 32 + blk * 2 + ihalf;

    float hprev[4] = {0.f, 0.f, 0.f, 0.f};
    __syncthreads();  // AnL fill complete (only barrier in the kernel)

#pragma unroll 1
    for (int t = 0; t < T_; ++t) {
        int par = t & 1;
        if (t) {
            // wait: all 32 producers of this batch ring published h^(t-1)
            while (1) {
                unsigned f = (lane < 32)
                                 ? __hip_atomic_load(fpoll + lane, __ATOMIC_RELAXED, AGENT)
                                 : 0xffffffffu;
                if (__all((int)(f >= (unsigned)t))) break;
                __builtin_amdgcn_s_sleep(1);
            }
            __asm__ __volatile__("" ::: "memory");
        }

        // B-frags: h[b][k] bf16 from LLC, 8-deep pipelined pulls.
        const u16* hb = hx + par * 32768 + b * 512 + q * 8;
        f4v aR = {0.f, 0.f, 0.f, 0.f};
        f4v aZ = {0.f, 0.f, 0.f, 0.f};
        f4v aN = {0.f, 0.f, 0.f, 0.f};
        s8v hfp[8];
#pragma unroll
        for (int k = 0; k < 8; k++) hfp[k] = pull16(hb + k * 32);
#pragma unroll
        for (int k = 0; k < 8; k++) {
            s8v an = *(const s8v*)(AnL + (ihalf * 16 + k) * 64 + lane);
            aR = MFMA16(Ar[k], hfp[k], aR);
            aZ = MFMA16(Az[k], hfp[k], aZ);
            aN = MFMA16(an, hfp[k], aN);
            hfp[k] = pull16(hb + (k + 8) * 32);
        }
#pragma unroll
        for (int k = 0; k < 8; k++) {
            s8v an = *(const s8v*)(AnL + (ihalf * 16 + 8 + k) * 64 + lane);
            aR = MFMA16(Ar[k + 8], hfp[k], aR);
            aZ = MFMA16(Az[k + 8], hfp[k], aZ);
            aN = MFMA16(an, hfp[k], aN);
        }

        float xr[4] = {bflo(xR.x), bfhi(xR.x), bflo(xR.y), bfhi(xR.y)};
        float xz[4] = {bflo(xZ.x), bfhi(xZ.x), bflo(xZ.y), bfhi(xZ.y)};
        float xn[4] = {bflo(xN.x), bfhi(xN.x), bflo(xN.y), bfhi(xN.y)};
        float hnew[4];
#pragma unroll
        for (int j = 0; j < 4; j++) {
            float rg = sigmoidf_(xr[j] + aR[j] + bhr[j]);
            float zg = sigmoidf_(xz[j] + aZ[j] + bhz[j]);
            float ng = tanhf_(xn[j] + rg * (aN[j] + bhn[j]));
            hnew[j] = (1.f - zg) * ng + zg * hprev[j];
            hprev[j] = hnew[j];
        }

        // publish: ONE 8B agent store (4 consecutive i for batch b), drain, flag.
        u64t pk = (u64t)f2bf(hnew[0]) | ((u64t)f2bf(hnew[1]) << 16) |
                  ((u64t)f2bf(hnew[2]) << 32) | ((u64t)f2bf(hnew[3]) << 48);
        __hip_atomic_store((u64t*)(hx + (par ^ 1) * 32768 + b * 512 + ibase), pk,
                           __ATOMIC_RELAXED, AGENT);
        __asm__ __volatile__("s_waitcnt vmcnt(0)" ::: "memory");
        if (lane == 0)
            __hip_atomic_store(fself, (unsigned)(t + 1), __ATOMIC_RELAXED, AGENT);

        // hseq (f32, [t][b][h]) after the drain: off the critical path.
        f4v hv = {hnew[0], hnew[1], hnew[2], hnew[3]};
        *(f4v*)(hseq + ((size_t)t * B_ + b) * H_ + ibase) = hv;

        // prefetch xp for t+1 (lands during next poll)
        int tn = (t + 1 < T_) ? t + 1 : t;
        const u16* xpt = xpb + (size_t)tn * G_;
        xR = *(const uint2*)(xpt);
        xZ = *(const uint2*)(xpt + 512);
        xN = *(const uint2*)(xpt + 1024);
    }
}

// ---------- decay-weighted & plain sums of h_seq, 8 t-chunks ----------
__global__ __launch_bounds__(512) void k_hw8(const float* __restrict__ hseq,
                                             const float* __restrict__ decay,
                                             float* __restrict__ hwT,
                                             float* __restrict__ hsumT) {
    int b = blockIdx.x & 63, chunk = blockIdx.x >> 6;
    int h = threadIdx.x;
    int t0 = chunk * 128;
    float aw = 0.f, as = 0.f;
    for (int tt = 0; tt < 128; tt++) {
        float v = hseq[((size_t)(t0 + tt) * B_ + b) * H_ + h];
        aw = fmaf(decay[t0 + tt], v, aw);
        as += v;
    }
    atomicAdd(&hwT[h * B_ + b], aw);
    atomicAdd(&hsumT[h * B_ + b], as);
}

// ---------- spreads, chunked over t (8 chunks) + atomicAdd ----------
__global__ __launch_bounds__(512) void k_sd8(const float* __restrict__ hseq,
                                             const float* __restrict__ ws,
                                             const float* __restrict__ bs,
                                             const float* __restrict__ decay,
                                             float* __restrict__ flatT) {
    int b = blockIdx.x & 63, chunk = blockIdx.x >> 6;
    int t0 = chunk * 128;
    int tid = threadIdx.x;
    __shared__ float hl[2][512];
    int c = tid >> 4, p = tid & 15;
    float wreg[32];
#pragma unroll
    for (int i = 0; i < 32; i++) wreg[i] = ws[c * H_ + p + 16 * i];
    float bsc = bs[c];
    float acc = 0.f;
    hl[0][tid] = hseq[((size_t)t0 * B_ + b) * H_ + tid];
    __syncthreads();
    for (int tt = 0; tt < 128; tt++) {
        float nxt = 0.f;
        if (tt < 127) nxt = hseq[((size_t)(t0 + tt + 1) * B_ + b) * H_ + tid];
        int pg = tt & 1;
        float partial = 0.f;
#pragma unroll
        for (int i = 0; i < 32; i++) partial = fmaf(wreg[i], hl[pg][p + 16 * i], partial);
        partial += __shfl_xor(partial, 1, 16);
        partial += __shfl_xor(partial, 2, 16);
        partial += __shfl_xor(partial, 4, 16);
        partial += __shfl_xor(partial, 8, 16);
        acc = fmaf(decay[t0 + tt], sigmoidf_(partial + bsc), acc);
        __syncthreads();
        hl[pg ^ 1][tid] = nxt;
        __syncthreads();
    }
    if (p == 0) atomicAdd(&flatT[(c * 514 + 512) * B_ + b], 0.15f * acc);
}

// ---------- weights -> softmax -> nw rows ----------
__global__ __launch_bounds__(1024) void k_weights(const float* __restrict__ hsumT,
                                                  const float* __restrict__ ww,
                                                  const float* __restrict__ bw,
                                                  float* __restrict__ flatT) {
    int tid = threadIdx.x;
    __shared__ float wmat[C_ * B_];
    __shared__ float mb[B_], sb[B_];
    int b = tid & 63;
    int c0 = tid >> 6;
    float a0 = 0.f, a1 = 0.f;
    for (int h = 0; h < H_; h++) {
        float hv = hsumT[h * B_ + b];
        a0 = fmaf(ww[c0 * H_ + h], hv, a0);
        a1 = fmaf(ww[(c0 + 16) * H_ + h], hv, a1);
    }
    wmat[c0 * B_ + b] = a0 + 1024.0f * bw[c0];
    wmat[(c0 + 16) * B_ + b] = a1 + 1024.0f * bw[c0 + 16];
    __syncthreads();
    if (tid < 64) {
        float m = -1e30f;
        for (int c = 0; c < C_; c++) m = fmaxf(m, wmat[c * B_ + tid]);
        float sum = 0.f;
        for (int c = 0; c < C_; c++) sum += __expf(wmat[c * B_ + tid] - m);
        mb[tid] = m;
        sb[tid] = 1.0f / sum;
    }
    __syncthreads();
    flatT[(c0 * 514 + 513) * B_ + b] = __expf(wmat[c0 * B_ + b] - mb[b]) * sb[b];
    flatT[((c0 + 16) * 514 + 513) * B_ + b] = __expf(wmat[(c0 + 16) * B_ + b] - mb[b]) * sb[b];
}

// ---------- centers rows ----------
__global__ __launch_bounds__(64) void k_centersT(const float* __restrict__ hwT,
                                                 const float* __restrict__ wc,
                                                 const float* __restrict__ bc,
                                                 float* __restrict__ flatT) {
    int b = threadIdx.x;
    int k0 = blockIdx.x * 8;
    float acc[8] = {0, 0, 0, 0, 0, 0, 0, 0};
    for (int h = 0; h < H_; h++) {
        float hv = hwT[h * B_ + b];
#pragma unroll
        for (int r = 0; r < 8; r++) acc[r] = fmaf(wc[(size_t)(k0 + r) * H_ + h], hv, acc[r]);
    }
#pragma unroll
    for (int r = 0; r < 8; r++) {
        int k = k0 + r;
        int c = k >> 9, i = k & 511;
        flatT[(c * 514 + i) * B_ + b] = 0.15f * (acc[r] + (1.0f / 0.15f) * bc[k]);
    }
}

// ---------- classifier ----------
__global__ __launch_bounds__(256) void k_cls(const float* __restrict__ flatT,
                                             const float* __restrict__ wcls,
                                             const float* __restrict__ bcls,
                                             float* __restrict__ out) {
    int tid = threadIdx.x;
    int wv = tid >> 6, b = tid & 63;
    int j0 = blockIdx.x * 8;
    __shared__ float red[4][8][64];
    float acc[8] = {0, 0, 0, 0, 0, 0, 0, 0};
    for (int i = 0; i < 4112; i++) {
        int k = wv * 4112 + i;
        float fv = flatT[k * B_ + b];
#pragma unroll
        for (int r = 0; r < 8; r++) acc[r] = fmaf(wcls[(size_t)(j0 + r) * KCLS_ + k], fv, acc[r]);
    }
#pragma unroll
    for (int r = 0; r < 8; r++) red[wv][r][b] = acc[r];
    __syncthreads();
    for (int rr = tid; rr < 512; rr += 256) {
        int r = rr >> 6, bb = rr & 63;
        float sum = red[0][r][bb] + red[1][r][bb] + red[2][r][bb] + red[3][r][bb];
        out[bb * NCLS_ + j0 + r] = sum + bcls[j0 + r];
    }
}

extern "C" void kernel_launch(void* const* d_in, const int* in_sizes, int n_in,
                              void* d_out, int out_size, void* d_ws, size_t ws_size,
                              hipStream_t stream) {
    const int*   tokens = (const int*)d_in[0];
    const float* emb    = (const float*)d_in[1];
    const float* w_ih   = (const float*)d_in[2];
    const float* w_hh   = (const float*)d_in[3];
    const float* b_ih   = (const float*)d_in[4];
    const float* b_hh   = (const float*)d_in[5];
    const float* wc     = (const float*)d_in[6];
    const float* bc     = (const float*)d_in[7];
    const float* ws     = (const float*)d_in[8];
    const float* bs     = (const float*)d_in[9];
    const float* ww     = (const float*)d_in[10];
    const float* bw     = (const float*)d_in[11];
    const float* wcls   = (const float*)d_in[12];
    const float* bcls   = (const float*)d_in[13];
    float* out = (float*)d_out;

    char* w = (char*)d_ws;
    u16*      xp    = (u16*)(w + 0);                 // 201,326,592
    float*    hseq  = (float*)(w + 201326592);       // 134,217,728
    u16*      X16   = (u16*)(w + 335544320);         //  67,108,864 (dead after k_xp)
    u16*      Wih16 = (u16*)(w + 402653184);         //   1,572,864
    uint4*    Apk   = (uint4*)(w + 404226048);       //   1,572,864
    float*    decay = (float*)(w + 405798912);       //       4,096
    float*    hwT   = (float*)(w + 405803008);       //     131,072
    float*    hsumT = (float*)(w + 405934080);       //     131,072
    float*    flatT = (float*)(w + 406065152);       //   4,210,688
    // aliased into X16's region after k_xp:
    u16*      hx    = (u16*)(w + 335544320);                   // 2*64*512*2 = 131,072
    unsigned* flags = (unsigned*)(w + 335544320 + 131072);     // 128*4      =      512

    k_cast_wih<<<dim3((G_ * H_ + 255) / 256), dim3(256), 0, stream>>>(w_ih, Wih16);
    k_packA<<<dim3(384), dim3(256), 0, stream>>>(w_hh, Apk);
    k_decay<<<dim3(4), dim3(256), 0, stream>>>(decay);
    k_zero<<<dim3((1118208 + 255) / 256), dim3(256), 0, stream>>>(hwT, 1118208);
    k_embed<<<dim3(16384), dim3(256), 0, stream>>>(tokens, emb, X16);
    k_xp<<<dim3(12288), dim3(256), 0, stream>>>(X16, Wih16, b_ih, xp);
    // zero hx (both parities) + flags; aliases X16 so must follow k_xp
    k_zero<<<dim3(129), dim3(256), 0, stream>>>((float*)hx, 32896);
    k_scan_mfma<<<dim3(16), dim3(512), 0, stream>>>(Apk, xp, b_hh, hseq, hx, flags);
    k_hw8<<<dim3(512), dim3(512), 0, stream>>>(hseq, decay, hwT, hsumT);
    k_sd8<<<dim3(512), dim3(512), 0, stream>>>(hseq, ws, bs, decay, flatT);
    k_weights<<<dim3(1), dim3(1024), 0, stream>>>(hsumT, ww, bw, flatT);
    k_centersT<<<dim3(2048), dim3(64), 0, stream>>>(hwT, wc, bc, flatT);
    k_cls<<<dim3(125), dim3(256), 0, stream>>>(flatT, wcls, bcls, out);
}